// Round 13
// baseline (441.947 us; speedup 1.0000x reference)
//
#include <hip/hip_runtime.h>
#include <cstdint>
#include <cstddef>

#define NT   8192
#define DIN  1024
#define DFF  4096
#define DOUT 1024
#define NEXP 8

typedef float  f32x4v __attribute__((ext_vector_type(4)));
typedef short  s16x8  __attribute__((ext_vector_type(8)));
typedef short  s16x4  __attribute__((ext_vector_type(4)));

__device__ __forceinline__ ushort f2bf(float f) {
  union { float f; uint32_t u; } c; c.f = f;
  uint32_t u = c.u;
  return (ushort)((u + 0x7fffu + ((u >> 16) & 1u)) >> 16);  // RNE
}

// ---------------- router: 1 block = 64 tokens, block-level atomic reduction --
__global__ __launch_bounds__(256) void router_kernel(
    const float* __restrict__ x, const float* __restrict__ sw,
    const float* __restrict__ sb,
    int* __restrict__ routes, int* __restrict__ posArr,
    float* __restrict__ pmaxArr,
    int* __restrict__ cnt, float* __restrict__ probsum) {
  __shared__ int   sRoute[64];
  __shared__ float sProb[4][NEXP];
  __shared__ int   sBase[NEXP];

  const int lane = threadIdx.x & 63;
  const int w    = threadIdx.x >> 6;
  const int t0   = blockIdx.x * 64;

  float bias[NEXP];
#pragma unroll
  for (int e = 0; e < NEXP; e++) bias[e] = sb[e];

  float wprob[NEXP];
#pragma unroll
  for (int e = 0; e < NEXP; e++) wprob[e] = 0.0f;

  for (int k = 0; k < 16; k++) {
    const int t = t0 + w * 16 + k;
    const float* xr = x + (size_t)t * DIN;
    float acc[NEXP];
#pragma unroll
    for (int e = 0; e < NEXP; e++) acc[e] = 0.0f;
#pragma unroll
    for (int it = 0; it < DIN / 64; it++) {
      const int i = it * 64 + lane;
      const float xv = xr[i];
      const float4 s0 = *(const float4*)(sw + (size_t)i * NEXP);
      const float4 s1 = *(const float4*)(sw + (size_t)i * NEXP + 4);
      acc[0] += xv * s0.x; acc[1] += xv * s0.y; acc[2] += xv * s0.z; acc[3] += xv * s0.w;
      acc[4] += xv * s1.x; acc[5] += xv * s1.y; acc[6] += xv * s1.z; acc[7] += xv * s1.w;
    }
#pragma unroll
    for (int e = 0; e < NEXP; e++) {
#pragma unroll
      for (int off = 32; off > 0; off >>= 1) acc[e] += __shfl_xor(acc[e], off, 64);
    }
    float m = acc[0] + bias[0]; int am = 0;
    float lg[NEXP];
#pragma unroll
    for (int e = 0; e < NEXP; e++) {
      lg[e] = acc[e] + bias[e];
      if (lg[e] > m) { m = lg[e]; am = e; }
    }
    float esum = 0.0f;
    float pe[NEXP];
#pragma unroll
    for (int e = 0; e < NEXP; e++) { pe[e] = __expf(lg[e] - m); esum += pe[e]; }
    const float inv = 1.0f / esum;
#pragma unroll
    for (int e = 0; e < NEXP; e++) wprob[e] += pe[e] * inv;
    if (lane == 0) {
      routes[t] = am;
      pmaxArr[t] = inv;           // pe[am] == 1 -> pmax = 1/esum
      sRoute[w * 16 + k] = am;
    }
  }
  if (lane == 0) {
#pragma unroll
    for (int e = 0; e < NEXP; e++) sProb[w][e] = wprob[e];
  }
  __syncthreads();

  const int tid = threadIdx.x;
  if (tid < NEXP) {
    float s = sProb[0][tid] + sProb[1][tid] + sProb[2][tid] + sProb[3][tid];
    atomicAdd(&probsum[tid], s);
    int c = 0;
#pragma unroll
    for (int j = 0; j < 64; j++) c += (sRoute[j] == tid);
    sBase[tid] = atomicAdd(&cnt[tid], c);
  }
  __syncthreads();

  if (tid < 64) {
    const int r = sRoute[tid];
    int rank = 0;
    for (int j = 0; j < 64; j++) rank += (j < tid) & (sRoute[j] == r);
    posArr[t0 + tid] = sBase[r] + rank;
  }
}

// ---------------- offsets (exclusive scan of 8) + aux loss -------------------
__global__ void offsets_aux_kernel(const int* __restrict__ cnt, const float* __restrict__ probsum,
                                   int* __restrict__ offsets, float* __restrict__ auxout) {
  if (threadIdx.x == 0) {
    int o = 0; float aux = 0.0f;
    for (int e = 0; e < NEXP; e++) {
      offsets[e] = o; o += cnt[e];
      aux += (float)cnt[e] * probsum[e];
    }
    offsets[NEXP] = o;
    auxout[0] = aux * ((float)NEXP / (float)NT);
  }
}

// ---------------- gather tokens into expert-contiguous bf16 rows -------------
__global__ void gather_kernel(const float* __restrict__ x, const int* __restrict__ routes,
                              const int* __restrict__ posArr, const int* __restrict__ offsets,
                              int* __restrict__ perm, ushort* __restrict__ Xg) {
  const int lane = threadIdx.x & 63;
  const int t = (blockIdx.x * blockDim.x + threadIdx.x) >> 6;
  if (t >= NT) return;
  const int slot = offsets[routes[t]] + posArr[t];
  if (lane == 0) perm[slot] = t;
  const float* src = x + (size_t)t * DIN;
  ushort* dst = Xg + (size_t)slot * DIN;
#pragma unroll
  for (int half = 0; half < 2; half++) {
    int i = half * 512 + lane * 8;
    float4 v0 = *(const float4*)(src + i);
    float4 v1 = *(const float4*)(src + i + 4);
    s16x8 p;
    p[0] = (short)f2bf(v0.x); p[1] = (short)f2bf(v0.y);
    p[2] = (short)f2bf(v0.z); p[3] = (short)f2bf(v0.w);
    p[4] = (short)f2bf(v1.x); p[5] = (short)f2bf(v1.y);
    p[6] = (short)f2bf(v1.z); p[7] = (short)f2bf(v1.w);
    *(s16x8*)(dst + i) = p;
  }
}

// ---------------- transpose + fp32->bf16: [E][K][N] -> [E][N][K] -------------
__global__ void transpose_cvt_kernel(const float* __restrict__ src, ushort* __restrict__ dst,
                                     const int K, const int N) {
  __shared__ float tile[64][65];
  const int ntn = N >> 6;
  const int ntk = K >> 6;
  int b = blockIdx.x;
  const int tn = b % ntn; b /= ntn;
  const int tk = b % ntk; const int e = b / ntk;
  const float* s = src + ((size_t)e * K + (size_t)tk * 64) * N + (size_t)tn * 64;
  const int c4 = (threadIdx.x & 15) * 4;
  const int r0 = threadIdx.x >> 4;  // 0..15
#pragma unroll
  for (int p = 0; p < 4; p++) {
    const int row = r0 + p * 16;
    float4 v = *(const float4*)(s + (size_t)row * N + c4);
    tile[row][c4 + 0] = v.x; tile[row][c4 + 1] = v.y;
    tile[row][c4 + 2] = v.z; tile[row][c4 + 3] = v.w;
  }
  __syncthreads();
  ushort* d = dst + ((size_t)e * N + (size_t)tn * 64) * K + (size_t)tk * 64;
#pragma unroll
  for (int p = 0; p < 4; p++) {
    const int nrow = r0 + p * 16;
    s16x4 o;
    o[0] = (short)f2bf(tile[c4 + 0][nrow]);
    o[1] = (short)f2bf(tile[c4 + 1][nrow]);
    o[2] = (short)f2bf(tile[c4 + 2][nrow]);
    o[3] = (short)f2bf(tile[c4 + 3][nrow]);
    *(s16x4*)(d + (size_t)nrow * K + c4) = o;
  }
}

#define GLD16(g, l)                                                                        \
  __builtin_amdgcn_global_load_lds((const __attribute__((address_space(1))) uint32_t*)(g), \
                                   (__attribute__((address_space(3))) uint32_t*)(l), 16, 0, 0)

// ======== 128x128 / BK=64 / 4-wave / 2 blocks/CU m97-style grouped GEMM ======
// Rationale (R12): per-block schedules plateau at ~43% resident-MfmaUtil with
// 1 block/CU because barrier drains leave the CU empty. The verified m97/m103
// design (multiple blocks/CU, simple stage->read->MFMA->__syncthreads loop,
// compiler-scheduled waits, m114 implicit cross-BLOCK overlap) fills those
// drains with the other block's waves. LDS 64KB (2buf x (16+16)KB) -> 2
// blocks/CU; VGPR ~160 under (256,2) cap=256 (no spill).
// Wave (wr=wid>>1, wc=wid&1) owns 64x64 output. Swizzle: (row,kslot16B) at
// phys kslot^(row&7), pre-swizzled global source + linear LDS dest (rule #21).
// EPI==0 (GEMM1): flat grid 2560 = 8e x (32bx x 10by), expert->XCD chunk
//   swizzle (bid&7 = XCD = expert group; FETCH 200->52MB, R8 evidence).
// EPI==1 (GEMM2): dim3 grid, fp32 scatter with bias+pmax; L3-resident.
template <int KDIM, int EPI>
__global__ __launch_bounds__(256, 2) void moe_gemm128_kernel(
    const ushort* __restrict__ A,   // [slots][KDIM] bf16 expert-contiguous
    const ushort* __restrict__ BT,  // [E][N][KDIM] bf16
    const float* __restrict__ bias, // [E][N]
    const int* __restrict__ offsets,
    ushort* __restrict__ Hout,      // EPI==0: [slots][N] bf16 (relu)
    float* __restrict__ Y,          // EPI==1: [NT][N] fp32 scatter
    const int* __restrict__ perm, const float* __restrict__ pmaxArr,
    const int N) {
  __shared__ ushort sA[2][128 * 64];   // 16KB per buf, swizzled
  __shared__ ushort sB[2][128 * 64];
  int e, bx, by;
  if constexpr (EPI == 0) {
    // grid = 2560 = 8 XCD-chunks x 320; expert e = chunk (all on one XCD).
    const int logical = (blockIdx.x & 7) * 320 + (blockIdx.x >> 3);
    e = logical / 320;                 // == blockIdx.x & 7
    const int rem = logical - e * 320;
    bx = rem & 31;                     // 32 n-blocks (DFF/128)
    by = rem >> 5;                     // 10 m-blocks (cnt <= 1280)
  } else {
    bx = blockIdx.x; by = blockIdx.y; e = blockIdx.z;
  }
  const int mlimit = offsets[e + 1];
  const int m0 = offsets[e] + by * 128;
  if (m0 >= mlimit) return;
  const int n0 = bx * 128;
  const int tid = threadIdx.x;
  const int lane = tid & 63;
  const int wid = tid >> 6;
  const int wr = wid >> 1;   // 0..1 : m 64-group
  const int wc = wid & 1;    // 0..1 : n 64-group
  const int rsel = lane & 15;
  const int lhi = lane >> 4; // 0..3

  // staging: 256 thr x 16B = 4KB = 32 rows per chunk; 4 chunks per 16KB tile.
  // row = c*32 + (tid>>3); row&7 = (tid>>3)&7 -> pre-swizzle source column.
  const int srow = tid >> 3;                           // 0..31
  const int scol = ((tid & 7) ^ ((tid >> 3) & 7)) * 8; // pre-swizzled col
  const ushort* gA = A + (size_t)(m0 + srow) * KDIM + scol;
  const ushort* gB = BT + ((size_t)e * N + n0 + srow) * KDIM + scol;
  const int ldst = tid * 8;  // elem offset; chunks at +2048 elems (32 rows)
  const size_t LK = (size_t)KDIM;

#define STAGE(buf, kt)                                                     \
  do {                                                                     \
    const ushort* ga_ = gA + (size_t)(kt) * 64;                            \
    const ushort* gb_ = gB + (size_t)(kt) * 64;                            \
    GLD16(ga_, &sA[buf][ldst]);                                            \
    GLD16(ga_ + 32 * LK, &sA[buf][ldst + 2048]);                           \
    GLD16(ga_ + 64 * LK, &sA[buf][ldst + 4096]);                           \
    GLD16(ga_ + 96 * LK, &sA[buf][ldst + 6144]);                           \
    GLD16(gb_, &sB[buf][ldst]);                                            \
    GLD16(gb_ + 32 * LK, &sB[buf][ldst + 2048]);                           \
    GLD16(gb_ + 64 * LK, &sB[buf][ldst + 4096]);                           \
    GLD16(gb_ + 96 * LK, &sB[buf][ldst + 6144]);                           \
  } while (0)

  f32x4v acc[4][4];   // [mf][nf]
#pragma unroll
  for (int mf = 0; mf < 4; mf++)
#pragma unroll
    for (int nf = 0; nf < 4; nf++) acc[mf][nf] = (f32x4v)0.0f;

  const int rsw = rsel & 7;
  const int sw0 = ((lhi) ^ rsw) * 8;       // phys 16B-slot, k-step 0
  const int sw1 = ((4 + lhi) ^ rsw) * 8;   // phys 16B-slot, k-step 1
  int arow[4], brow[4];
#pragma unroll
  for (int mf = 0; mf < 4; mf++) arow[mf] = (wr * 64 + mf * 16 + rsel) * 64;
#pragma unroll
  for (int nf = 0; nf < 4; nf++) brow[nf] = (wc * 64 + nf * 16 + rsel) * 64;

  constexpr int NS = KDIM / 64;
  STAGE(0, 0);
  __syncthreads();
  int cur = 0;
  for (int t = 0; t < NS; ++t) {
    if (t + 1 < NS) STAGE(cur ^ 1, t + 1);   // issue next-tile loads FIRST
    s16x8 a[4][2], b[4][2];
#pragma unroll
    for (int mf = 0; mf < 4; mf++) {
      a[mf][0] = *(const s16x8*)&sA[cur][arow[mf] + sw0];
      a[mf][1] = *(const s16x8*)&sA[cur][arow[mf] + sw1];
    }
#pragma unroll
    for (int nf = 0; nf < 4; nf++) {
      b[nf][0] = *(const s16x8*)&sB[cur][brow[nf] + sw0];
      b[nf][1] = *(const s16x8*)&sB[cur][brow[nf] + sw1];
    }
#pragma unroll
    for (int mf = 0; mf < 4; mf++)
#pragma unroll
      for (int nf = 0; nf < 4; nf++)
#pragma unroll
        for (int ks = 0; ks < 2; ks++)
          acc[mf][nf] = __builtin_amdgcn_mfma_f32_16x16x32_bf16(
              a[mf][ks], b[nf][ks], acc[mf][nf], 0, 0, 0);
    __syncthreads();   // drains vmcnt+lgkm: next buf landed, cur reads done
    cur ^= 1;
  }
#undef STAGE

  // epilogue: wave's 64x64 at (m0 + wr*64, n0 + wc*64)
  float bv[4];
#pragma unroll
  for (int nf = 0; nf < 4; nf++)
    bv[nf] = bias[(size_t)e * N + n0 + wc * 64 + nf * 16 + rsel];
#pragma unroll
  for (int mf = 0; mf < 4; mf++) {
#pragma unroll
    for (int r = 0; r < 4; r++) {
      const int grow = m0 + wr * 64 + mf * 16 + lhi * 4 + r;
      if (grow < mlimit) {
        if constexpr (EPI == 0) {
          ushort* hrow = Hout + (size_t)grow * N + n0 + wc * 64;
#pragma unroll
          for (int nf = 0; nf < 4; nf++) {
            float v = acc[mf][nf][r] + bv[nf];
            hrow[nf * 16 + rsel] = f2bf(fmaxf(v, 0.0f));
          }
        } else {
          const int tok = perm[grow];
          const float sc = pmaxArr[tok];
          float* yrow = Y + (size_t)tok * N + n0 + wc * 64;
#pragma unroll
          for (int nf = 0; nf < 4; nf++)
            yrow[nf * 16 + rsel] = (acc[mf][nf][r] + bv[nf]) * sc;
        }
      }
    }
  }
}

// ---------------------------------------------------------------------------
extern "C" void kernel_launch(void* const* d_in, const int* in_sizes, int n_in,
                              void* d_out, int out_size, void* d_ws, size_t ws_size,
                              hipStream_t stream) {
  const float* x  = (const float*)d_in[0];
  const float* sw = (const float*)d_in[1];
  const float* sb = (const float*)d_in[2];
  const float* w1 = (const float*)d_in[3];
  const float* b1 = (const float*)d_in[4];
  const float* w2 = (const float*)d_in[5];
  const float* b2 = (const float*)d_in[6];
  float* out = (float*)d_out;
  float* auxp = out + (size_t)NT * DOUT;

  char* wsb = (char*)d_ws;
  int*   cnt      = (int*)wsb;               // 8 ints
  float* probsum  = (float*)(wsb + 32);      // 8 floats
  int*   offsets  = (int*)(wsb + 64);        // 9 ints
  int*   routes   = (int*)(wsb + 256);
  int*   posArr   = routes + NT;
  float* pmaxArr  = (float*)(posArr + NT);
  int*   perm     = (int*)(pmaxArr + NT);
  ushort* Xg = (ushort*)(wsb + 256 + (size_t)4 * 4 * NT);           // [NT+256][DIN]
  ushort* Hg = Xg + (size_t)(NT + 256) * DIN;                       // [NT+256][DFF]
  ushort* Wt = Hg + (size_t)(NT + 256) * DFF;                       // E*DFF*DIN bf16, reused
  size_t needed = (size_t)((char*)Wt - wsb) + (size_t)NEXP * DFF * DIN * 2;
  if (ws_size < needed) return;  // insufficient scratch; fail validation visibly

  hipMemsetAsync(d_ws, 0, 64, stream);  // cnt + probsum

  router_kernel<<<NT / 64, 256, 0, stream>>>(x, sw, sb, routes, posArr, pmaxArr, cnt, probsum);
  offsets_aux_kernel<<<1, 64, 0, stream>>>(cnt, probsum, offsets, auxp);
  gather_kernel<<<NT / 4, 256, 0, stream>>>(x, routes, posArr, offsets, perm, Xg);

  // w1: [E][DIN][DFF] -> Wt [E][DFF][DIN]
  transpose_cvt_kernel<<<NEXP * (DIN / 64) * (DFF / 64), 256, 0, stream>>>(w1, Wt, DIN, DFF);
  // GEMM1: flat 2560 = 8 experts x (32bx x 10by), expert->XCD chunk swizzle;
  // ~2560 launched, ~2050 live -> 4 rounds at 2 blocks/CU.
  moe_gemm128_kernel<DIN, 0><<<2560, 256, 0, stream>>>(
      Xg, Wt, b1, offsets, Hg, nullptr, nullptr, nullptr, DFF);

  // w2: [E][DFF][DOUT] -> Wt [E][DOUT][DFF]  (reuse Wt; stream-ordered)
  transpose_cvt_kernel<<<NEXP * (DFF / 64) * (DOUT / 64), 256, 0, stream>>>(w2, Wt, DFF, DOUT);
  // GEMM2: dim3(8, 10, 8) = 640 launched, ~545 live -> ~1.06 rounds at
  // 2 blocks/CU (512 slots): coverage fixed without split-K.
  moe_gemm128_kernel<DFF, 1><<<dim3(DOUT / 128, 10, NEXP), 256, 0, stream>>>(
      Hg, Wt, b2, offsets, nullptr, out, perm, pmaxArr, DOUT);
}